// Round 1
// baseline (189.326 us; speedup 1.0000x reference)
//
#include <hip/hip_runtime.h>

#define PI_F 3.14159265358979323846f

__device__ __forceinline__ float rcpf_(float x){ return __builtin_amdgcn_rcpf(x); }
__device__ __forceinline__ float rsqf_(float x){ return __builtin_amdgcn_rsqf(x); }
__device__ __forceinline__ float sqrtf_(float x){ return __builtin_amdgcn_sqrtf(x); }

__device__ __forceinline__ float schlick5(float u){
    float m = fminf(fmaxf(1.0f - u, 0.0f), 1.0f);
    float m2 = m * m;
    return m2 * m2 * m;
}

// 4 points per thread: 6x float4 in (96B, 16-aligned), 3x float4 out (48B, 16-aligned)
__global__ __launch_bounds__(256) void brdf_kernel(
    const float* __restrict__ in,          // (N,2,3)
    const float* __restrict__ base_color,  // 3
    const float* __restrict__ metallic,
    const float* __restrict__ subsurface,
    const float* __restrict__ specular,
    const float* __restrict__ roughness,
    const float* __restrict__ specular_tint,
    const float* __restrict__ anisotropic,
    const float* __restrict__ sheen,
    const float* __restrict__ sheen_tint,
    const float* __restrict__ clear_coat,
    const float* __restrict__ clear_coat_gloss,
    float* __restrict__ out,               // (N,3)
    int npts)
{
    // ---------------- uniform (per-launch) derivations ----------------
    const float mtl     = metallic[0];
    const float sub     = subsurface[0];
    const float spec    = specular[0];
    const float rough   = roughness[0];
    const float sp_tint = specular_tint[0];
    const float aniso   = anisotropic[0];
    const float sh      = sheen[0];
    const float sh_tint = sheen_tint[0];
    const float cc      = clear_coat[0];
    const float ccg     = clear_coat_gloss[0];

    const float cd0 = __powf(base_color[0], 2.2f);
    const float cd1 = __powf(base_color[1], 2.2f);
    const float cd2 = __powf(base_color[2], 2.2f);
    const float lum = 0.3f*cd0 + 0.6f*cd1 + 0.1f*cd2;
    const float il  = rcpf_(fmaxf(lum, 1e-20f));
    const float ct0 = (lum > 0.f) ? cd0*il : 0.f;
    const float ct1 = (lum > 0.f) ? cd1*il : 0.f;
    const float ct2 = (lum > 0.f) ? cd2*il : 0.f;

    const float s008 = spec * 0.08f;
    const float b0 = s008 * (1.f + sp_tint*(ct0 - 1.f));
    const float b1 = s008 * (1.f + sp_tint*(ct1 - 1.f));
    const float b2 = s008 * (1.f + sp_tint*(ct2 - 1.f));
    const float cs0_0 = b0 + mtl*(cd0 - b0);   // c_spec0
    const float cs0_1 = b1 + mtl*(cd1 - b1);
    const float cs0_2 = b2 + mtl*(cd2 - b2);

    const float om = 1.f - mtl;
    const float invpi = 1.f / PI_F;
    const float dcol0 = cd0 * om * invpi;      // diffuse color weight
    const float dcol1 = cd1 * om * invpi;
    const float dcol2 = cd2 * om * invpi;
    const float scol0 = sh * (1.f + sh_tint*(ct0 - 1.f)) * om;  // sheen weight
    const float scol1 = sh * (1.f + sh_tint*(ct1 - 1.f)) * om;
    const float scol2 = sh * (1.f + sh_tint*(ct2 - 1.f)) * om;

    const float two_rough = 2.f * rough;

    const float aspect = sqrtf_(1.f - aniso*0.9f);
    const float r2 = rough * rough;
    const float ax = fmaxf(0.001f, r2 * rcpf_(aspect));
    const float ay = fmaxf(0.001f, r2 * aspect);
    const float ax2 = ax*ax, ay2 = ay*ay;
    const float inv_ax2 = rcpf_(ax2);
    const float inv_ay2 = rcpf_(ay2);
    const float k_ds = rcpf_(PI_F * ax * ay);

    const float a_cc = 0.1f + (0.001f - 0.1f)*ccg;
    const float a2 = a_cc * a_cc;
    float a2m1, k_dr;
    if (a_cc >= 1.0f) { a2m1 = 0.f; k_dr = invpi; }
    else              { a2m1 = a2 - 1.f; k_dr = (a2 - 1.f) * rcpf_(PI_F * __logf(a2)); }
    const float cc_q = 0.25f * cc;

    // ---------------- per-point work ----------------
    int t = blockIdx.x * blockDim.x + threadIdx.x;
    long base = (long)t * 4;
    if (base >= npts) return;

    const float4* in4 = reinterpret_cast<const float4*>(in) + (size_t)t * 6;
    float4 q0 = in4[0], q1 = in4[1], q2 = in4[2], q3 = in4[3], q4 = in4[4], q5 = in4[5];

    const float px[4][6] = {
        {q0.x, q0.y, q0.z, q0.w, q1.x, q1.y},
        {q1.z, q1.w, q2.x, q2.y, q2.z, q2.w},
        {q3.x, q3.y, q3.z, q3.w, q4.x, q4.y},
        {q4.z, q4.w, q5.x, q5.y, q5.z, q5.w},
    };
    float ox[4][3];

#pragma unroll
    for (int k = 0; k < 4; ++k) {
        const float l0 = px[k][0], l1 = px[k][1], l2 = px[k][2];
        const float v0 = px[k][3], v1 = px[k][4], v2 = px[k][5];

        float hx = l0 + v0, hy = l1 + v1, hz = l2 + v2;
        const float inv = rsqf_(hx*hx + hy*hy + hz*hz);
        hx *= inv; hy *= inv; hz *= inv;

        const float cnh = hz;
        const float chl = hx*l0 + hy*l1 + hz*l2;

        const bool valid = (l2 >= 0.f) && (v2 >= 0.f);
        const float cnl = valid ? l2 : 0.5f;
        const float cnv = valid ? v2 : 0.5f;

        const float fl = schlick5(cnl);
        const float fv = schlick5(cnv);
        const float FH = schlick5(chl);

        const float chl2 = chl * chl;
        const float fd90m1  = two_rough * chl2 - 0.5f;
        const float fd  = (1.f + fd90m1*fl) * (1.f + fd90m1*fv);
        const float fss90m1 = rough * chl2 - 1.f;
        const float fss = (1.f + fss90m1*fl) * (1.f + fss90m1*fv);
        const float ss = 1.25f * (fss * (rcpf_(cnl + cnv) - 0.5f) + 0.5f);
        const float dw = fd + sub * (ss - fd);          // lerp(fd, ss, sub)

        // anisotropic GGX specular
        const float dterm = hx*hx*inv_ax2 + hy*hy*inv_ay2 + cnh*cnh;
        const float Ds = k_ds * rcpf_(dterm * dterm);
        const float GsL = rcpf_(cnl + sqrtf_(l0*l0*ax2 + l1*l1*ay2 + cnl*cnl));
        const float GsV = rcpf_(cnv + sqrtf_(v0*v0*ax2 + v1*v1*ay2 + cnv*cnv));
        const float GsDs = GsL * GsV * Ds;

        // clearcoat
        const float tcc = 1.f + a2m1 * cnh * cnh;
        const float Dr = k_dr * rcpf_(tcc);
        const float GrL = rcpf_(cnl + sqrtf_(0.0625f + 0.9375f*cnl*cnl));
        const float GrV = rcpf_(cnv + sqrtf_(0.0625f + 0.9375f*cnv*cnv));
        const float Fr = 0.04f + 0.96f * FH;
        const float clear = cc_q * GrL * GrV * Fr * Dr;

        float o0 = dw*dcol0 + FH*scol0 + GsDs*(cs0_0 + FH*(1.f - cs0_0)) + clear;
        float o1 = dw*dcol1 + FH*scol1 + GsDs*(cs0_1 + FH*(1.f - cs0_1)) + clear;
        float o2 = dw*dcol2 + FH*scol2 + GsDs*(cs0_2 + FH*(1.f - cs0_2)) + clear;

        ox[k][0] = valid ? o0 : 0.f;
        ox[k][1] = valid ? o1 : 0.f;
        ox[k][2] = valid ? o2 : 0.f;
    }

    float4* out4 = reinterpret_cast<float4*>(out) + (size_t)t * 3;
    out4[0] = make_float4(ox[0][0], ox[0][1], ox[0][2], ox[1][0]);
    out4[1] = make_float4(ox[1][1], ox[1][2], ox[2][0], ox[2][1]);
    out4[2] = make_float4(ox[2][2], ox[3][0], ox[3][1], ox[3][2]);
}

extern "C" void kernel_launch(void* const* d_in, const int* in_sizes, int n_in,
                              void* d_out, int out_size, void* d_ws, size_t ws_size,
                              hipStream_t stream) {
    const float* in = (const float*)d_in[0];
    const int npts = in_sizes[0] / 6;           // (N,2,3) -> N
    const int nthreads = npts / 4;              // 4 points per thread (N % 4 == 0)
    const int block = 256;
    const int grid = (nthreads + block - 1) / block;

    brdf_kernel<<<grid, block, 0, stream>>>(
        in,
        (const float*)d_in[1],  // base_color (3)
        (const float*)d_in[2],  // metallic
        (const float*)d_in[3],  // subsurface
        (const float*)d_in[4],  // specular
        (const float*)d_in[5],  // roughness
        (const float*)d_in[6],  // specular_tint
        (const float*)d_in[7],  // anisotropic
        (const float*)d_in[8],  // sheen
        (const float*)d_in[9],  // sheen_tint
        (const float*)d_in[10], // clear_coat
        (const float*)d_in[11], // clear_coat_gloss
        (float*)d_out, npts);
}

// Round 2
// 187.322 us; speedup vs baseline: 1.0107x; 1.0107x over previous
//
#include <hip/hip_runtime.h>

#define PI_F 3.14159265358979323846f

__device__ __forceinline__ float rcpf_(float x){ return __builtin_amdgcn_rcpf(x); }
__device__ __forceinline__ float sqrtf_(float x){ return __builtin_amdgcn_sqrtf(x); }

// m in [0,1] by construction (inputs are unit vectors, z>=0); clamp dropped.
__device__ __forceinline__ float schlick5(float u){
    float m = 1.0f - u;
    float m2 = m * m;
    return m2 * m2 * m;
}

// Derived-uniform layout in d_ws (22 floats):
// 0:rough 1:sub 2:ax2 3:ay2 4:inv_ax2 5:inv_ay2 6:k_ds 7:a2m1 8:k_dr 9:cc_q
// 10..12:dcol 13..15:scol 16..18:cs0 19..21:(1-cs0)
__device__ __forceinline__ void compute_uniforms(
    const float* bc, float mtl, float sub, float spec, float rough,
    float sp_tint, float aniso, float sh, float sh_tint, float cc, float ccg,
    float* u)
{
    const float cd0 = __powf(bc[0], 2.2f);
    const float cd1 = __powf(bc[1], 2.2f);
    const float cd2 = __powf(bc[2], 2.2f);
    const float lum = 0.3f*cd0 + 0.6f*cd1 + 0.1f*cd2;
    const float il  = rcpf_(fmaxf(lum, 1e-20f));
    const float ct0 = (lum > 0.f) ? cd0*il : 0.f;
    const float ct1 = (lum > 0.f) ? cd1*il : 0.f;
    const float ct2 = (lum > 0.f) ? cd2*il : 0.f;

    const float s008 = spec * 0.08f;
    const float b0 = s008 * (1.f + sp_tint*(ct0 - 1.f));
    const float b1 = s008 * (1.f + sp_tint*(ct1 - 1.f));
    const float b2 = s008 * (1.f + sp_tint*(ct2 - 1.f));
    const float cs0_0 = b0 + mtl*(cd0 - b0);
    const float cs0_1 = b1 + mtl*(cd1 - b1);
    const float cs0_2 = b2 + mtl*(cd2 - b2);

    const float om = 1.f - mtl;
    const float invpi = 1.f / PI_F;

    const float aspect = sqrtf_(1.f - aniso*0.9f);
    const float r2 = rough * rough;
    const float ax = fmaxf(0.001f, r2 * rcpf_(aspect));
    const float ay = fmaxf(0.001f, r2 * aspect);

    const float a_cc = 0.1f + (0.001f - 0.1f)*ccg;
    const float a2 = a_cc * a_cc;
    float a2m1, k_dr;
    if (a_cc >= 1.0f) { a2m1 = 0.f; k_dr = invpi; }
    else              { a2m1 = a2 - 1.f; k_dr = (a2 - 1.f) * rcpf_(PI_F * __logf(a2)); }

    u[0] = rough;
    u[1] = sub;
    u[2] = ax*ax;
    u[3] = ay*ay;
    u[4] = rcpf_(ax*ax);
    u[5] = rcpf_(ay*ay);
    u[6] = rcpf_(PI_F * ax * ay);
    u[7] = a2m1;
    u[8] = k_dr;
    u[9] = 0.25f * cc;
    u[10] = cd0 * om * invpi;
    u[11] = cd1 * om * invpi;
    u[12] = cd2 * om * invpi;
    u[13] = sh * (1.f + sh_tint*(ct0 - 1.f)) * om;
    u[14] = sh * (1.f + sh_tint*(ct1 - 1.f)) * om;
    u[15] = sh * (1.f + sh_tint*(ct2 - 1.f)) * om;
    u[16] = cs0_0;
    u[17] = cs0_1;
    u[18] = cs0_2;
    u[19] = 1.f - cs0_0;
    u[20] = 1.f - cs0_1;
    u[21] = 1.f - cs0_2;
}

__global__ void setup_kernel(
    const float* __restrict__ bc, const float* __restrict__ metallic,
    const float* __restrict__ subsurface, const float* __restrict__ specular,
    const float* __restrict__ roughness, const float* __restrict__ specular_tint,
    const float* __restrict__ anisotropic, const float* __restrict__ sheen,
    const float* __restrict__ sheen_tint, const float* __restrict__ clear_coat,
    const float* __restrict__ clear_coat_gloss, float* __restrict__ ws)
{
    if (threadIdx.x == 0) {
        float u[22];
        compute_uniforms(bc, metallic[0], subsurface[0], specular[0], roughness[0],
                         specular_tint[0], anisotropic[0], sheen[0], sheen_tint[0],
                         clear_coat[0], clear_coat_gloss[0], u);
        #pragma unroll
        for (int i = 0; i < 22; ++i) ws[i] = u[i];
    }
}

// 4 points per thread: 6x float4 in (96B), 3x float4 out (48B)
template<bool USE_WS>
__global__ __launch_bounds__(256) void brdf_kernel(
    const float* __restrict__ in,          // (N,2,3)
    const float* __restrict__ uws,         // 22 derived uniforms (if USE_WS)
    const float* __restrict__ bc, const float* __restrict__ metallic,
    const float* __restrict__ subsurface, const float* __restrict__ specular,
    const float* __restrict__ roughness, const float* __restrict__ specular_tint,
    const float* __restrict__ anisotropic, const float* __restrict__ sheen,
    const float* __restrict__ sheen_tint, const float* __restrict__ clear_coat,
    const float* __restrict__ clear_coat_gloss,
    float* __restrict__ out,               // (N,3)
    int npts)
{
    float U[22];
    if constexpr (USE_WS) {
        #pragma unroll
        for (int i = 0; i < 22; ++i) U[i] = uws[i];
    } else {
        compute_uniforms(bc, metallic[0], subsurface[0], specular[0], roughness[0],
                         specular_tint[0], anisotropic[0], sheen[0], sheen_tint[0],
                         clear_coat[0], clear_coat_gloss[0], U);
    }
    const float rough   = U[0],  sub     = U[1];
    const float ax2     = U[2],  ay2     = U[3];
    const float inv_ax2 = U[4],  inv_ay2 = U[5];
    const float k_ds    = U[6],  a2m1    = U[7];
    const float k_dr    = U[8],  cc_q    = U[9];
    const float two_rough = 2.f * rough;

    int t = blockIdx.x * blockDim.x + threadIdx.x;
    if ((long)t * 4 >= npts) return;

    const float4* in4 = reinterpret_cast<const float4*>(in) + (size_t)t * 6;
    float4 q0 = in4[0], q1 = in4[1], q2 = in4[2], q3 = in4[3], q4 = in4[4], q5 = in4[5];

    const float px[4][6] = {
        {q0.x, q0.y, q0.z, q0.w, q1.x, q1.y},
        {q1.z, q1.w, q2.x, q2.y, q2.z, q2.w},
        {q3.x, q3.y, q3.z, q3.w, q4.x, q4.y},
        {q4.z, q4.w, q5.x, q5.y, q5.z, q5.w},
    };
    float ox[4][3];

#pragma unroll
    for (int k = 0; k < 4; ++k) {
        const float l0 = px[k][0], l1 = px[k][1], l2 = px[k][2];
        const float v0 = px[k][3], v1 = px[k][4], v2 = px[k][5];

        // un-normalized half vector; for unit l,v: |hv|^2 = 2+2 l.v and
        // cos_hl = (hv.l)/|hv| = |hv|/2  (since hv.l = |hv|^2/2)
        const float hvx = l0 + v0, hvy = l1 + v1, hvz = l2 + v2;
        const float n2 = hvx*hvx + hvy*hvy + hvz*hvz;
        const float chl = 0.5f * sqrtf_(n2);     // cos_hl
        const float chl2 = 0.25f * n2;           // cos_hl^2 (exact)

        const bool valid = (l2 >= 0.f) && (v2 >= 0.f);
        const float cnl = valid ? l2 : 0.5f;
        const float cnv = valid ? v2 : 0.5f;

        const float fl = schlick5(cnl);
        const float fv = schlick5(cnv);
        const float FH = schlick5(chl);

        const float fd90m1  = two_rough * chl2 - 0.5f;
        const float fd  = (1.f + fd90m1*fl) * (1.f + fd90m1*fv);
        const float fss90m1 = rough * chl2 - 1.f;
        const float fss = (1.f + fss90m1*fl) * (1.f + fss90m1*fv);
        const float ss = 1.25f * (fss * (rcpf_(cnl + cnv) - 0.5f) + 0.5f);
        const float dw = fd + sub * (ss - fd);   // lerp(fd, ss, sub)

        // anisotropic GGX specular, over un-normalized hv:
        //   dterm = dtermu / n2, Ds = k_ds * n2^2 / dtermu^2
        //   Gs*Ds folded into ONE rcp
        const float dtermu = hvx*hvx*inv_ax2 + hvy*hvy*inv_ay2 + hvz*hvz;
        const float denL = cnl + sqrtf_(l0*l0*ax2 + l1*l1*ay2 + cnl*cnl);
        const float denV = cnv + sqrtf_(v0*v0*ax2 + v1*v1*ay2 + cnv*cnv);
        const float n2_2 = n2 * n2;
        const float GsDs = k_ds * n2_2 * rcpf_(dtermu*dtermu * denL * denV);

        // clearcoat: t = 1 + a2m1*cnh^2, cnh^2 = hvz^2/n2
        //   Dr = k_dr * n2 / (n2 + a2m1*hvz^2); whole term folded into ONE rcp
        const float tden = n2 + a2m1 * (hvz*hvz);
        const float grL = cnl + sqrtf_(0.0625f + 0.9375f*cnl*cnl);
        const float grV = cnv + sqrtf_(0.0625f + 0.9375f*cnv*cnv);
        const float Fr = 0.04f + 0.96f * FH;
        const float clear = cc_q * Fr * k_dr * n2 * rcpf_(tden * grL * grV);

        float o0 = dw*U[10] + FH*U[13] + GsDs*(U[16] + FH*U[19]) + clear;
        float o1 = dw*U[11] + FH*U[14] + GsDs*(U[17] + FH*U[20]) + clear;
        float o2 = dw*U[12] + FH*U[15] + GsDs*(U[18] + FH*U[21]) + clear;

        ox[k][0] = valid ? o0 : 0.f;
        ox[k][1] = valid ? o1 : 0.f;
        ox[k][2] = valid ? o2 : 0.f;
    }

    float4* out4 = reinterpret_cast<float4*>(out) + (size_t)t * 3;
    out4[0] = make_float4(ox[0][0], ox[0][1], ox[0][2], ox[1][0]);
    out4[1] = make_float4(ox[1][1], ox[1][2], ox[2][0], ox[2][1]);
    out4[2] = make_float4(ox[2][2], ox[3][0], ox[3][1], ox[3][2]);
}

extern "C" void kernel_launch(void* const* d_in, const int* in_sizes, int n_in,
                              void* d_out, int out_size, void* d_ws, size_t ws_size,
                              hipStream_t stream) {
    const float* in = (const float*)d_in[0];
    const int npts = in_sizes[0] / 6;           // (N,2,3) -> N
    const int nthreads = npts / 4;              // 4 points per thread
    const int block = 256;
    const int grid = (nthreads + block - 1) / block;

    const float* bc  = (const float*)d_in[1];
    const float* p2  = (const float*)d_in[2];
    const float* p3  = (const float*)d_in[3];
    const float* p4  = (const float*)d_in[4];
    const float* p5  = (const float*)d_in[5];
    const float* p6  = (const float*)d_in[6];
    const float* p7  = (const float*)d_in[7];
    const float* p8  = (const float*)d_in[8];
    const float* p9  = (const float*)d_in[9];
    const float* p10 = (const float*)d_in[10];
    const float* p11 = (const float*)d_in[11];

    if (ws_size >= 22 * sizeof(float) && d_ws != nullptr) {
        float* ws = (float*)d_ws;
        setup_kernel<<<1, 64, 0, stream>>>(bc, p2, p3, p4, p5, p6, p7, p8, p9, p10, p11, ws);
        brdf_kernel<true><<<grid, block, 0, stream>>>(
            in, ws, bc, p2, p3, p4, p5, p6, p7, p8, p9, p10, p11,
            (float*)d_out, npts);
    } else {
        brdf_kernel<false><<<grid, block, 0, stream>>>(
            in, nullptr, bc, p2, p3, p4, p5, p6, p7, p8, p9, p10, p11,
            (float*)d_out, npts);
    }
}